// Round 22
// baseline (292.011 us; speedup 1.0000x reference)
//
#include <hip/hip_runtime.h>
#include <hip/hip_bf16.h>

// EdgeConv, CSR-by-dst, bf16 intermediates:
//   abf[n] = bf16(h@W1[0:64]); bsf[n] = bf16(h@W1[64:128]+b1)
//   acc[n] = sum_{e:dst=n} relu(abf[src] + bsf[n] + e*w128)   (wave/node, lane=feat)
//   out[n] = acc[n] @ W2 + cnt[n]*b2                          (fused readlane matvec)
// R22 = R21 (186.8us best) + coarse pre blocks for role OVERLAP. pre_count's
//   roles are complementary (pre: VALU-bound; count/scatter: memory-bound) but
//   ran serially (117 = 62+55): 782 pre blocks > ~512 resident-block capacity,
//   so count started only as pre drained. PRE_NPB 128->512 (outer x4 loop per
//   wave around the byte-identical inner body; wreg amortized 4x) -> 196 pre
//   blocks co-resident with ~316 streaming count blocks from t=0. R15's failed
//   interleave starved pre; this keeps one pre block pinned per CU.
//   Decisive counters: VGPR ~48 & FETCH ~35MB = body unperturbed.
// node_accum: R3 body + padded beg + packed-W2 dwordx4 epilogue (R21).
// pipeline: padded-by-64 scatter (R17); classic fallback if ws too small.

#define PRE_NPB 512   // precompute: nodes per block (4 waves x 128 nodes, x4 loop)
#define PADK 64       // padded path: max edges per node

typedef unsigned int u32;

// ---------------- offset allocation, single global cursor (classic path) ----------------
__global__ __launch_bounds__(256) void alloc_offs_kernel(const int* __restrict__ counts,
                                                         int* __restrict__ gcursor,
                                                         int* __restrict__ offs, int n) {
    __shared__ int wsum[4];
    const int i    = blockIdx.x * 256 + threadIdx.x;
    const int lane = threadIdx.x & 63;
    const int wv   = threadIdx.x >> 6;

    const int c = (i < n) ? counts[i] : 0;
    int incl = c;
    #pragma unroll
    for (int d = 1; d < 64; d <<= 1) {
        int v = __shfl_up(incl, d, 64);
        if (lane >= d) incl += v;
    }
    const int excl = incl - c;
    if (lane == 63) wsum[wv] = incl;
    __syncthreads();
    if (threadIdx.x == 0) {
        const int s0 = wsum[0], s1 = wsum[1], s2 = wsum[2], s3 = wsum[3];
        const int b = atomicAdd(gcursor, s0 + s1 + s2 + s3);
        wsum[0] = b; wsum[1] = b + s0; wsum[2] = b + s0 + s1; wsum[3] = b + s0 + s1 + s2;
    }
    __syncthreads();
    if (i < n) offs[i] = wsum[wv] + excl;
}

// ---------------- single-pass non-atomic fill (classic path) ----------------
__global__ void fill_kernel(const int* __restrict__ dst, const int* __restrict__ src,
                            const float* __restrict__ e,
                            const int* __restrict__ offs, const int* __restrict__ rank,
                            int2* __restrict__ meta, int n_edges) {
    const int i = blockIdx.x * blockDim.x + threadIdx.x;
    if (i >= n_edges) return;
    const int d = dst[i];
    meta[offs[d] + rank[i]] = make_int2(src[i], __float_as_int(e[i]));
}

// ---------------- fused: precompute (blocks < pg) + count/scatter (blocks >= pg) ----------------
// precompute (R12 inner body, byte-for-byte; outer x4 node-loop per wave).
// count role: atomic rank + scatter (padded) or rank store (classic). First
// count-role block (bid==pg) also packs W2 -> w2p.
__global__ __launch_bounds__(256, 2) void pre_count_kernel(
    const float* __restrict__ h, const float* __restrict__ W1, const float* __restrict__ b1,
    unsigned short* __restrict__ abf, unsigned short* __restrict__ bsf, int n_nodes,
    const int* __restrict__ dst, const int* __restrict__ src, const float* __restrict__ e,
    int* __restrict__ counts, int2* __restrict__ meta2, int* __restrict__ rank,
    const float* __restrict__ W2, float* __restrict__ w2p,
    int n_edges, int pg, int padK)
{
    const int lane = threadIdx.x & 63;
    const int wv   = threadIdx.x >> 6;

    if ((int)blockIdx.x >= pg) {
        // ---- count (+scatter) role ----
        if ((int)blockIdx.x == pg) {
            // pack W2 -> w2p (4096 floats, 16 per thread), once per launch
            #pragma unroll
            for (int u = 0; u < 16; ++u) {
                const int idx = threadIdx.x * 16 + u;
                const int q = idx >> 8, l = (idx >> 2) & 63, c = idx & 3;
                w2p[idx] = W2[(size_t)(4 * q + c) * 64 + l];
            }
        }
        const int i = ((int)blockIdx.x - pg) * 256 + threadIdx.x;
        if (i < n_edges) {
            const int d = dst[i];
            const int r = atomicAdd(&counts[d], 1);
            if (padK > 0)
                meta2[(size_t)d * padK + r] = make_int2(src[i], __float_as_int(e[i]));
            else
                rank[i] = r;
        }
        return;
    }

    // ---- precompute role: wave covers 128 nodes (4 x 32-node sub-tiles) ----
    const int wbase = blockIdx.x * PRE_NPB + wv * 128;
    if (wbase >= n_nodes) return;

    const float4* h4p = reinterpret_cast<const float4*>(h);

    // ---- pass A: av over W1[0:64] -> abf ----
    {
        float wreg[64];
        #pragma unroll
        for (int k = 0; k < 64; ++k) wreg[k] = W1[(size_t)k * 64 + lane];
        #pragma unroll
        for (int k = 0; k < 64; ++k) asm volatile("" : "+v"(wreg[k]));

        for (int t = 0; t < 4; ++t) {
            const int nbase = wbase + t * 32;
            if (nbase >= n_nodes) break;

            auto ldgrp = [&](int g) -> float4 {
                float4 v = make_float4(0.f, 0.f, 0.f, 0.f);
                const int row = nbase + 4 * g + (lane >> 4);
                if (g < 8 && row < n_nodes)
                    v = h4p[(size_t)(nbase + 4 * g) * 16 + lane];
                return v;
            };

            float4 cur = ldgrp(0);
            for (int g = 0; g < 8; ++g) {
                const float4 nxt = ldgrp(g + 1);        // prefetch next group
                #pragma unroll
                for (int nn = 0; nn < 4; ++nn) {
                    const int n = nbase + 4 * g + nn;
                    if (n < n_nodes) {
                        float av = 0.f;
                        #pragma unroll
                        for (int k4 = 0; k4 < 16; ++k4) {
                            const int sl = nn * 16 + k4;   // imm lane after unroll
                            const float h0 = __uint_as_float(__builtin_amdgcn_readlane(__float_as_uint(cur.x), sl));
                            const float h1 = __uint_as_float(__builtin_amdgcn_readlane(__float_as_uint(cur.y), sl));
                            const float h2 = __uint_as_float(__builtin_amdgcn_readlane(__float_as_uint(cur.z), sl));
                            const float h3 = __uint_as_float(__builtin_amdgcn_readlane(__float_as_uint(cur.w), sl));
                            av = fmaf(h0, wreg[4 * k4 + 0], av);   // same chain order
                            av = fmaf(h1, wreg[4 * k4 + 1], av);
                            av = fmaf(h2, wreg[4 * k4 + 2], av);
                            av = fmaf(h3, wreg[4 * k4 + 3], av);
                        }
                        __hip_bfloat16 ab = __float2bfloat16(av);
                        abf[(size_t)n * 64 + lane] = *reinterpret_cast<unsigned short*>(&ab);
                    }
                }
                cur = nxt;
            }
        }
    }

    // ---- pass B: bv over W1[64:128] + b1 -> bsf ----
    {
        float wreg[64];
        #pragma unroll
        for (int k = 0; k < 64; ++k) wreg[k] = W1[(size_t)(64 + k) * 64 + lane];
        #pragma unroll
        for (int k = 0; k < 64; ++k) asm volatile("" : "+v"(wreg[k]));
        const float b1l = b1[lane];

        for (int t = 0; t < 4; ++t) {
            const int nbase = wbase + t * 32;
            if (nbase >= n_nodes) break;

            auto ldgrp = [&](int g) -> float4 {
                float4 v = make_float4(0.f, 0.f, 0.f, 0.f);
                const int row = nbase + 4 * g + (lane >> 4);
                if (g < 8 && row < n_nodes)
                    v = h4p[(size_t)(nbase + 4 * g) * 16 + lane];
                return v;
            };

            float4 cur = ldgrp(0);
            for (int g = 0; g < 8; ++g) {
                const float4 nxt = ldgrp(g + 1);
                #pragma unroll
                for (int nn = 0; nn < 4; ++nn) {
                    const int n = nbase + 4 * g + nn;
                    if (n < n_nodes) {
                        float bv = b1l;
                        #pragma unroll
                        for (int k4 = 0; k4 < 16; ++k4) {
                            const int sl = nn * 16 + k4;
                            const float h0 = __uint_as_float(__builtin_amdgcn_readlane(__float_as_uint(cur.x), sl));
                            const float h1 = __uint_as_float(__builtin_amdgcn_readlane(__float_as_uint(cur.y), sl));
                            const float h2 = __uint_as_float(__builtin_amdgcn_readlane(__float_as_uint(cur.z), sl));
                            const float h3 = __uint_as_float(__builtin_amdgcn_readlane(__float_as_uint(cur.w), sl));
                            bv = fmaf(h0, wreg[4 * k4 + 0], bv);   // same chain order
                            bv = fmaf(h1, wreg[4 * k4 + 1], bv);
                            bv = fmaf(h2, wreg[4 * k4 + 2], bv);
                            bv = fmaf(h3, wreg[4 * k4 + 3], bv);
                        }
                        __hip_bfloat16 bb = __float2bfloat16(bv);
                        bsf[(size_t)n * 64 + lane] = *reinterpret_cast<unsigned short*>(&bb);
                    }
                }
                cur = nxt;
            }
        }
    }
}

// ---------------- accum: wave/node, lane=feat, register-meta + depth-8 prefetch,
// ---------------- epilogue W2 via packed dwordx4 (16 loads/node) ----------------
__global__ __launch_bounds__(256) void node_accum_kernel(
    const unsigned short* __restrict__ abf, const unsigned short* __restrict__ bsf,
    const float* __restrict__ W1, const float* __restrict__ w2p, const float* __restrict__ b2,
    const int* __restrict__ offs, const int* __restrict__ counts,
    const int2* __restrict__ meta, float* __restrict__ out, int n_nodes, int padK)
{
    const int lane = threadIdx.x & 63;
    const int wv   = __builtin_amdgcn_readfirstlane(threadIdx.x >> 6);
    const int n    = blockIdx.x * 4 + wv;          // wave-uniform node id
    if (n >= n_nodes) return;

    const float basel = __uint_as_float((uint)bsf[(size_t)n * 64 + lane] << 16);
    const float w128l = W1[(size_t)128 * 64 + lane];
    float acc = 0.f;

    const int beg = (padK > 0) ? n * padK : offs[n];   // s_load / SALU (n uniform)
    const int np  = counts[n];                          // s_load

    // chunks of <=64 edges: meta staged into registers by ONE lane-parallel load,
    // per-edge src/e extracted with v_readlane (no memory on the gather-addr path)
    for (int c0 = 0; c0 < np; c0 += 64) {
        const int cn = min(np - c0, 64);

        int mx = 0, my = 0;
        if (lane < cn) {
            const int2 m = meta[beg + c0 + lane];   // 512B coalesced, once per chunk
            mx = m.x; my = m.y;
        }

        // pipeline slots hold the RAW zext ushort; <<16 happens at consume time
        uint x0=0,x1=0,x2=0,x3=0,x4=0,x5=0,x6=0,x7=0;

        auto ld = [&](int j, uint& x) {
            const int s = __builtin_amdgcn_readlane(mx, j);        // uniform src id
            x = (uint)abf[(size_t)s * 64 + lane];                  // saddr gather, 128B/wave
        };
        auto step = [&](int j, uint xr) {
            const float ev = __uint_as_float((uint)__builtin_amdgcn_readlane(my, j));
            const float xv = __uint_as_float(xr << 16);
            acc += fmaxf(fmaf(ev, w128l, basel) + xv, 0.f);
        };

        if (cn > 0) ld(0, x0);
        if (cn > 1) ld(1, x1);
        if (cn > 2) ld(2, x2);
        if (cn > 3) ld(3, x3);
        if (cn > 4) ld(4, x4);
        if (cn > 5) ld(5, x5);
        if (cn > 6) ld(6, x6);
        if (cn > 7) ld(7, x7);

        int i = 0;
        while (i + 16 <= cn) {
            step(i + 0, x0); ld(i + 8,  x0);
            step(i + 1, x1); ld(i + 9,  x1);
            step(i + 2, x2); ld(i + 10, x2);
            step(i + 3, x3); ld(i + 11, x3);
            step(i + 4, x4); ld(i + 12, x4);
            step(i + 5, x5); ld(i + 13, x5);
            step(i + 6, x6); ld(i + 14, x6);
            step(i + 7, x7); ld(i + 15, x7);
            i += 8;
        }
        const int r = cn - i;   // 0..15
        if (r > 0)  { step(i + 0, x0); }  if (r > 8)  { ld(i + 8,  x0); }
        if (r > 1)  { step(i + 1, x1); }  if (r > 9)  { ld(i + 9,  x1); }
        if (r > 2)  { step(i + 2, x2); }  if (r > 10) { ld(i + 10, x2); }
        if (r > 3)  { step(i + 3, x3); }  if (r > 11) { ld(i + 11, x3); }
        if (r > 4)  { step(i + 4, x4); }  if (r > 12) { ld(i + 12, x4); }
        if (r > 5)  { step(i + 5, x5); }  if (r > 13) { ld(i + 13, x5); }
        if (r > 6)  { step(i + 6, x6); }  if (r > 14) { ld(i + 14, x6); }
        if (r > 7)  { step(i + 7, x7); }
        if (r > 8)  { step(i + 8,  x0); }
        if (r > 9)  { step(i + 9,  x1); }
        if (r > 10) { step(i + 10, x2); }
        if (r > 11) { step(i + 11, x3); }
        if (r > 12) { step(i + 12, x4); }
        if (r > 13) { step(i + 13, x5); }
        if (r > 14) { step(i + 14, x6); }
    }

    // fused epilogue: out[n][lane] = sum_j acc_j * W2[j][lane] + np*b2[lane]
    // packed W2: 16x dwordx4 (lane stride 16B, coalesced, L1-hot); j = 4q+c
    // ascending -> identical fma order to the 64x dword version.
    float o = (float)np * b2[lane];
    const float4* w2p4 = reinterpret_cast<const float4*>(w2p);
    #pragma unroll
    for (int q = 0; q < 16; ++q) {
        const float4 w4 = w2p4[q * 64 + lane];
        o = fmaf(__shfl(acc, 4 * q + 0, 64), w4.x, o);     // v_readlane (imm)
        o = fmaf(__shfl(acc, 4 * q + 1, 64), w4.y, o);
        o = fmaf(__shfl(acc, 4 * q + 2, 64), w4.z, o);
        o = fmaf(__shfl(acc, 4 * q + 3, 64), w4.w, o);
    }
    out[(size_t)n * 64 + lane] = o;
}

extern "C" void kernel_launch(void* const* d_in, const int* in_sizes, int n_in,
                              void* d_out, int out_size, void* d_ws, size_t ws_size,
                              hipStream_t stream) {
    const float* h  = (const float*)d_in[0];
    const float* e  = (const float*)d_in[1];
    const int* src  = (const int*)d_in[2];
    const int* dst  = (const int*)d_in[3];
    const float* W1 = (const float*)d_in[4];
    const float* b1 = (const float*)d_in[5];
    const float* W2 = (const float*)d_in[6];
    const float* b2 = (const float*)d_in[7];
    float* out = (float*)d_out;

    const int n_edges = in_sizes[2];
    const int N = in_sizes[0] / 64;

    const int eb = (n_edges + 255) / 256;
    const int nb = (N + 255) / 256;
    const int pg = (N + PRE_NPB - 1) / PRE_NPB;

    // padded path: counts(N+8) + w2p(4096 f) + meta2(N*PADK int2) + abf/bsf(256N B)
    const size_t need_pad = ((size_t)N + 8) * sizeof(int) + 4096 * sizeof(float)
                          + (size_t)N * PADK * sizeof(int2)
                          + (size_t)N * 256;

    int* counts = (int*)d_ws;

    if (ws_size >= need_pad) {
        // ---- padded path: memset -> pre_count(+scatter+pack) -> node_accum ----
        float* w2p  = (float*)(counts + N + 8);
        int2* meta2 = (int2*)(w2p + 4096);
        unsigned short* abf = (unsigned short*)(meta2 + (size_t)N * PADK);
        unsigned short* bsf = abf + (size_t)64 * N;

        hipMemsetAsync(counts, 0, ((size_t)N + 8) * sizeof(int), stream);
        pre_count_kernel<<<pg + eb, 256, 0, stream>>>(h, W1, b1, abf, bsf, N,
                                                      dst, src, e, counts, meta2,
                                                      nullptr, W2, w2p,
                                                      n_edges, pg, PADK);
        node_accum_kernel<<<(N + 3) / 4, 256, 0, stream>>>(abf, bsf, W1, w2p, b2,
                                                           nullptr, counts, meta2,
                                                           out, N, PADK);
    } else {
        // ---- classic path (R12 pipeline + packed-W2 epilogue) ----
        float* w2p   = (float*)(counts + N + 8);
        int* gcursor = (int*)(w2p + 4096);
        int* offs    = gcursor + 8;
        int* rank    = offs + N;
        int2* meta   = (int2*)(rank + n_edges);
        unsigned short* abf = (unsigned short*)(meta + n_edges);
        unsigned short* bsf = abf + (size_t)64 * N;

        hipMemsetAsync(counts, 0, ((size_t)N + 8) * sizeof(int), stream);
        hipMemsetAsync(gcursor, 0, 8 * sizeof(int), stream);
        pre_count_kernel<<<pg + eb, 256, 0, stream>>>(h, W1, b1, abf, bsf, N,
                                                      dst, src, e, counts, nullptr,
                                                      rank, W2, w2p,
                                                      n_edges, pg, 0);
        alloc_offs_kernel<<<nb, 256, 0, stream>>>(counts, gcursor, offs, N);
        fill_kernel<<<eb, 256, 0, stream>>>(dst, src, e, offs, rank, meta, n_edges);
        node_accum_kernel<<<(N + 3) / 4, 256, 0, stream>>>(abf, bsf, W1, w2p, b2,
                                                           offs, counts, meta,
                                                           out, N, 0);
    }
}

// Round 23
// 190.504 us; speedup vs baseline: 1.5328x; 1.5328x over previous
//
#include <hip/hip_runtime.h>
#include <hip/hip_bf16.h>

// EdgeConv, CSR-by-dst, bf16 intermediates:
//   abf[n] = bf16(h@W1[0:64]); bsf[n] = bf16(h@W1[64:128]+b1)
//   acc[n] = sum_{e:dst=n} relu(abf[src] + bsf[n] + e*w128)   (wave/node, lane=feat)
//   out[n] = acc[n] @ W2 + cnt[n]*b2                          (fused readlane matvec)
// R23 = R21 byte-for-byte (best: 186.8us). R22's coarse-pre overlap failed:
//   196 pre blocks x 4 waves = 784 waves < 1024 SIMDs -> pre under-parallelized
//   (occ 25%, VALUBusy 19%, 228us). Role overlap has now failed in BOTH
//   directions (R15 starved pre; R22 shrank pre below device width); the serial
//   62+55 split with full-width blocks is this structure's stable optimum.
// Components (each independently reproduced):
//   pre_count: R12 precompute body (x4 builds) + fused count/scatter + W2 pack.
//   node_accum: R3 edge loop (x6) + padded beg + packed-W2 dwordx4 epilogue.
//   pipeline: padded-by-64 scatter (R17, x3); classic fallback if ws too small.

#define PRE_NPB 128   // precompute: nodes per block (4 waves x 32 nodes)
#define PADK 64       // padded path: max edges per node

typedef unsigned int u32;

// ---------------- offset allocation, single global cursor (classic path) ----------------
__global__ __launch_bounds__(256) void alloc_offs_kernel(const int* __restrict__ counts,
                                                         int* __restrict__ gcursor,
                                                         int* __restrict__ offs, int n) {
    __shared__ int wsum[4];
    const int i    = blockIdx.x * 256 + threadIdx.x;
    const int lane = threadIdx.x & 63;
    const int wv   = threadIdx.x >> 6;

    const int c = (i < n) ? counts[i] : 0;
    int incl = c;
    #pragma unroll
    for (int d = 1; d < 64; d <<= 1) {
        int v = __shfl_up(incl, d, 64);
        if (lane >= d) incl += v;
    }
    const int excl = incl - c;
    if (lane == 63) wsum[wv] = incl;
    __syncthreads();
    if (threadIdx.x == 0) {
        const int s0 = wsum[0], s1 = wsum[1], s2 = wsum[2], s3 = wsum[3];
        const int b = atomicAdd(gcursor, s0 + s1 + s2 + s3);
        wsum[0] = b; wsum[1] = b + s0; wsum[2] = b + s0 + s1; wsum[3] = b + s0 + s1 + s2;
    }
    __syncthreads();
    if (i < n) offs[i] = wsum[wv] + excl;
}

// ---------------- single-pass non-atomic fill (classic path) ----------------
__global__ void fill_kernel(const int* __restrict__ dst, const int* __restrict__ src,
                            const float* __restrict__ e,
                            const int* __restrict__ offs, const int* __restrict__ rank,
                            int2* __restrict__ meta, int n_edges) {
    const int i = blockIdx.x * blockDim.x + threadIdx.x;
    if (i >= n_edges) return;
    const int d = dst[i];
    meta[offs[d] + rank[i]] = make_int2(src[i], __float_as_int(e[i]));
}

// ---------------- fused: precompute (blocks < pg) + count/scatter (blocks >= pg) ----------------
// precompute (R12 body, byte-for-byte). count role: atomic rank + scatter
// (padded) or rank store (classic). First count-role block (bid==pg) also packs
// W2 into w2p: w2p[q*256 + lane*4 + c] = W2[(4q+c)*64 + lane].
__global__ __launch_bounds__(256, 2) void pre_count_kernel(
    const float* __restrict__ h, const float* __restrict__ W1, const float* __restrict__ b1,
    unsigned short* __restrict__ abf, unsigned short* __restrict__ bsf, int n_nodes,
    const int* __restrict__ dst, const int* __restrict__ src, const float* __restrict__ e,
    int* __restrict__ counts, int2* __restrict__ meta2, int* __restrict__ rank,
    const float* __restrict__ W2, float* __restrict__ w2p,
    int n_edges, int pg, int padK)
{
    const int lane = threadIdx.x & 63;
    const int wv   = threadIdx.x >> 6;

    if ((int)blockIdx.x >= pg) {
        // ---- count (+scatter) role ----
        if ((int)blockIdx.x == pg) {
            // pack W2 -> w2p (4096 floats, 16 per thread), once per launch
            #pragma unroll
            for (int u = 0; u < 16; ++u) {
                const int idx = threadIdx.x * 16 + u;
                const int q = idx >> 8, l = (idx >> 2) & 63, c = idx & 3;
                w2p[idx] = W2[(size_t)(4 * q + c) * 64 + l];
            }
        }
        const int i = ((int)blockIdx.x - pg) * 256 + threadIdx.x;
        if (i < n_edges) {
            const int d = dst[i];
            const int r = atomicAdd(&counts[d], 1);
            if (padK > 0)
                meta2[(size_t)d * padK + r] = make_int2(src[i], __float_as_int(e[i]));
            else
                rank[i] = r;
        }
        return;
    }

    // ---- precompute role (R12 body) ----
    const int nbase = (blockIdx.x * 4 + wv) * 32;   // wave's 32 nodes
    if (nbase >= n_nodes) return;

    const float4* h4p = reinterpret_cast<const float4*>(h);

    auto ldgrp = [&](int g) -> float4 {
        float4 v = make_float4(0.f, 0.f, 0.f, 0.f);
        const int row = nbase + 4 * g + (lane >> 4);
        if (g < 8 && row < n_nodes)
            v = h4p[(size_t)(nbase + 4 * g) * 16 + lane];
        return v;
    };

    // ---- pass A: av over W1[0:64] -> abf ----
    {
        float wreg[64];
        #pragma unroll
        for (int k = 0; k < 64; ++k) wreg[k] = W1[(size_t)k * 64 + lane];
        #pragma unroll
        for (int k = 0; k < 64; ++k) asm volatile("" : "+v"(wreg[k]));

        float4 cur = ldgrp(0);
        for (int g = 0; g < 8; ++g) {
            const float4 nxt = ldgrp(g + 1);        // prefetch next group
            #pragma unroll
            for (int nn = 0; nn < 4; ++nn) {
                const int n = nbase + 4 * g + nn;
                if (n < n_nodes) {
                    float av = 0.f;
                    #pragma unroll
                    for (int k4 = 0; k4 < 16; ++k4) {
                        const int sl = nn * 16 + k4;   // imm lane after unroll
                        const float h0 = __uint_as_float(__builtin_amdgcn_readlane(__float_as_uint(cur.x), sl));
                        const float h1 = __uint_as_float(__builtin_amdgcn_readlane(__float_as_uint(cur.y), sl));
                        const float h2 = __uint_as_float(__builtin_amdgcn_readlane(__float_as_uint(cur.z), sl));
                        const float h3 = __uint_as_float(__builtin_amdgcn_readlane(__float_as_uint(cur.w), sl));
                        av = fmaf(h0, wreg[4 * k4 + 0], av);   // same chain order
                        av = fmaf(h1, wreg[4 * k4 + 1], av);
                        av = fmaf(h2, wreg[4 * k4 + 2], av);
                        av = fmaf(h3, wreg[4 * k4 + 3], av);
                    }
                    __hip_bfloat16 ab = __float2bfloat16(av);
                    abf[(size_t)n * 64 + lane] = *reinterpret_cast<unsigned short*>(&ab);
                }
            }
            cur = nxt;
        }
    }

    // ---- pass B: bv over W1[64:128] + b1 -> bsf ----
    {
        float wreg[64];
        #pragma unroll
        for (int k = 0; k < 64; ++k) wreg[k] = W1[(size_t)(64 + k) * 64 + lane];
        #pragma unroll
        for (int k = 0; k < 64; ++k) asm volatile("" : "+v"(wreg[k]));
        const float b1l = b1[lane];

        float4 cur = ldgrp(0);
        for (int g = 0; g < 8; ++g) {
            const float4 nxt = ldgrp(g + 1);
            #pragma unroll
            for (int nn = 0; nn < 4; ++nn) {
                const int n = nbase + 4 * g + nn;
                if (n < n_nodes) {
                    float bv = b1l;
                    #pragma unroll
                    for (int k4 = 0; k4 < 16; ++k4) {
                        const int sl = nn * 16 + k4;
                        const float h0 = __uint_as_float(__builtin_amdgcn_readlane(__float_as_uint(cur.x), sl));
                        const float h1 = __uint_as_float(__builtin_amdgcn_readlane(__float_as_uint(cur.y), sl));
                        const float h2 = __uint_as_float(__builtin_amdgcn_readlane(__float_as_uint(cur.z), sl));
                        const float h3 = __uint_as_float(__builtin_amdgcn_readlane(__float_as_uint(cur.w), sl));
                        bv = fmaf(h0, wreg[4 * k4 + 0], bv);   // same chain order
                        bv = fmaf(h1, wreg[4 * k4 + 1], bv);
                        bv = fmaf(h2, wreg[4 * k4 + 2], bv);
                        bv = fmaf(h3, wreg[4 * k4 + 3], bv);
                    }
                    __hip_bfloat16 bb = __float2bfloat16(bv);
                    bsf[(size_t)n * 64 + lane] = *reinterpret_cast<unsigned short*>(&bb);
                }
            }
            cur = nxt;
        }
    }
}

// ---------------- accum: wave/node, lane=feat, register-meta + depth-8 prefetch,
// ---------------- epilogue W2 via packed dwordx4 (16 loads/node, was 64) ----------------
__global__ __launch_bounds__(256) void node_accum_kernel(
    const unsigned short* __restrict__ abf, const unsigned short* __restrict__ bsf,
    const float* __restrict__ W1, const float* __restrict__ w2p, const float* __restrict__ b2,
    const int* __restrict__ offs, const int* __restrict__ counts,
    const int2* __restrict__ meta, float* __restrict__ out, int n_nodes, int padK)
{
    const int lane = threadIdx.x & 63;
    const int wv   = __builtin_amdgcn_readfirstlane(threadIdx.x >> 6);
    const int n    = blockIdx.x * 4 + wv;          // wave-uniform node id
    if (n >= n_nodes) return;

    const float basel = __uint_as_float((uint)bsf[(size_t)n * 64 + lane] << 16);
    const float w128l = W1[(size_t)128 * 64 + lane];
    float acc = 0.f;

    const int beg = (padK > 0) ? n * padK : offs[n];   // s_load / SALU (n uniform)
    const int np  = counts[n];                          // s_load

    // chunks of <=64 edges: meta staged into registers by ONE lane-parallel load,
    // per-edge src/e extracted with v_readlane (no memory on the gather-addr path)
    for (int c0 = 0; c0 < np; c0 += 64) {
        const int cn = min(np - c0, 64);

        int mx = 0, my = 0;
        if (lane < cn) {
            const int2 m = meta[beg + c0 + lane];   // 512B coalesced, once per chunk
            mx = m.x; my = m.y;
        }

        // pipeline slots hold the RAW zext ushort; <<16 happens at consume time
        uint x0=0,x1=0,x2=0,x3=0,x4=0,x5=0,x6=0,x7=0;

        auto ld = [&](int j, uint& x) {
            const int s = __builtin_amdgcn_readlane(mx, j);        // uniform src id
            x = (uint)abf[(size_t)s * 64 + lane];                  // saddr gather, 128B/wave
        };
        auto step = [&](int j, uint xr) {
            const float ev = __uint_as_float((uint)__builtin_amdgcn_readlane(my, j));
            const float xv = __uint_as_float(xr << 16);
            acc += fmaxf(fmaf(ev, w128l, basel) + xv, 0.f);
        };

        if (cn > 0) ld(0, x0);
        if (cn > 1) ld(1, x1);
        if (cn > 2) ld(2, x2);
        if (cn > 3) ld(3, x3);
        if (cn > 4) ld(4, x4);
        if (cn > 5) ld(5, x5);
        if (cn > 6) ld(6, x6);
        if (cn > 7) ld(7, x7);

        int i = 0;
        while (i + 16 <= cn) {
            step(i + 0, x0); ld(i + 8,  x0);
            step(i + 1, x1); ld(i + 9,  x1);
            step(i + 2, x2); ld(i + 10, x2);
            step(i + 3, x3); ld(i + 11, x3);
            step(i + 4, x4); ld(i + 12, x4);
            step(i + 5, x5); ld(i + 13, x5);
            step(i + 6, x6); ld(i + 14, x6);
            step(i + 7, x7); ld(i + 15, x7);
            i += 8;
        }
        const int r = cn - i;   // 0..15
        if (r > 0)  { step(i + 0, x0); }  if (r > 8)  { ld(i + 8,  x0); }
        if (r > 1)  { step(i + 1, x1); }  if (r > 9)  { ld(i + 9,  x1); }
        if (r > 2)  { step(i + 2, x2); }  if (r > 10) { ld(i + 10, x2); }
        if (r > 3)  { step(i + 3, x3); }  if (r > 11) { ld(i + 11, x3); }
        if (r > 4)  { step(i + 4, x4); }  if (r > 12) { ld(i + 12, x4); }
        if (r > 5)  { step(i + 5, x5); }  if (r > 13) { ld(i + 13, x5); }
        if (r > 6)  { step(i + 6, x6); }  if (r > 14) { ld(i + 14, x6); }
        if (r > 7)  { step(i + 7, x7); }
        if (r > 8)  { step(i + 8,  x0); }
        if (r > 9)  { step(i + 9,  x1); }
        if (r > 10) { step(i + 10, x2); }
        if (r > 11) { step(i + 11, x3); }
        if (r > 12) { step(i + 12, x4); }
        if (r > 13) { step(i + 13, x5); }
        if (r > 14) { step(i + 14, x6); }
    }

    // fused epilogue: out[n][lane] = sum_j acc_j * W2[j][lane] + np*b2[lane]
    // packed W2: 16x dwordx4 (lane stride 16B, coalesced, L1-hot); j = 4q+c
    // ascending -> identical fma order to the 64x dword version.
    float o = (float)np * b2[lane];
    const float4* w2p4 = reinterpret_cast<const float4*>(w2p);
    #pragma unroll
    for (int q = 0; q < 16; ++q) {
        const float4 w4 = w2p4[q * 64 + lane];
        o = fmaf(__shfl(acc, 4 * q + 0, 64), w4.x, o);     // v_readlane (imm)
        o = fmaf(__shfl(acc, 4 * q + 1, 64), w4.y, o);
        o = fmaf(__shfl(acc, 4 * q + 2, 64), w4.z, o);
        o = fmaf(__shfl(acc, 4 * q + 3, 64), w4.w, o);
    }
    out[(size_t)n * 64 + lane] = o;
}

extern "C" void kernel_launch(void* const* d_in, const int* in_sizes, int n_in,
                              void* d_out, int out_size, void* d_ws, size_t ws_size,
                              hipStream_t stream) {
    const float* h  = (const float*)d_in[0];
    const float* e  = (const float*)d_in[1];
    const int* src  = (const int*)d_in[2];
    const int* dst  = (const int*)d_in[3];
    const float* W1 = (const float*)d_in[4];
    const float* b1 = (const float*)d_in[5];
    const float* W2 = (const float*)d_in[6];
    const float* b2 = (const float*)d_in[7];
    float* out = (float*)d_out;

    const int n_edges = in_sizes[2];
    const int N = in_sizes[0] / 64;

    const int eb = (n_edges + 255) / 256;
    const int nb = (N + 255) / 256;
    const int pg = (N + PRE_NPB - 1) / PRE_NPB;

    // padded path: counts(N+8) + w2p(4096 f) + meta2(N*PADK int2) + abf/bsf(256N B)
    const size_t need_pad = ((size_t)N + 8) * sizeof(int) + 4096 * sizeof(float)
                          + (size_t)N * PADK * sizeof(int2)
                          + (size_t)N * 256;

    int* counts = (int*)d_ws;

    if (ws_size >= need_pad) {
        // ---- padded path: memset -> pre_count(+scatter+pack) -> node_accum ----
        float* w2p  = (float*)(counts + N + 8);
        int2* meta2 = (int2*)(w2p + 4096);
        unsigned short* abf = (unsigned short*)(meta2 + (size_t)N * PADK);
        unsigned short* bsf = abf + (size_t)64 * N;

        hipMemsetAsync(counts, 0, ((size_t)N + 8) * sizeof(int), stream);
        pre_count_kernel<<<pg + eb, 256, 0, stream>>>(h, W1, b1, abf, bsf, N,
                                                      dst, src, e, counts, meta2,
                                                      nullptr, W2, w2p,
                                                      n_edges, pg, PADK);
        node_accum_kernel<<<(N + 3) / 4, 256, 0, stream>>>(abf, bsf, W1, w2p, b2,
                                                           nullptr, counts, meta2,
                                                           out, N, PADK);
    } else {
        // ---- classic path (R12 pipeline + packed-W2 epilogue) ----
        float* w2p   = (float*)(counts + N + 8);
        int* gcursor = (int*)(w2p + 4096);
        int* offs    = gcursor + 8;
        int* rank    = offs + N;
        int2* meta   = (int2*)(rank + n_edges);
        unsigned short* abf = (unsigned short*)(meta + n_edges);
        unsigned short* bsf = abf + (size_t)64 * N;

        hipMemsetAsync(counts, 0, ((size_t)N + 8) * sizeof(int), stream);
        hipMemsetAsync(gcursor, 0, 8 * sizeof(int), stream);
        pre_count_kernel<<<pg + eb, 256, 0, stream>>>(h, W1, b1, abf, bsf, N,
                                                      dst, src, e, counts, nullptr,
                                                      rank, W2, w2p,
                                                      n_edges, pg, 0);
        alloc_offs_kernel<<<nb, 256, 0, stream>>>(counts, gcursor, offs, N);
        fill_kernel<<<eb, 256, 0, stream>>>(dst, src, e, offs, rank, meta, n_edges);
        node_accum_kernel<<<(N + 3) / 4, 256, 0, stream>>>(abf, bsf, W1, w2p, b2,
                                                           offs, counts, meta,
                                                           out, N, 0);
    }
}